// Round 1
// baseline (181.924 us; speedup 1.0000x reference)
//
#include <hip/hip_runtime.h>
#include <math.h>

#define DM1 63
#define WROW 64
#define RSIZE (DM1*WROW)   // 4032 floats per rel-side matrix / gelu-v block

// d_ws float offsets
#define OFF_V   0u
#define SZ_V    (1024u*RSIZE)
#define OFF_N   (OFF_V + SZ_V)
#define SZ_N    (1024u*64u)
#define OFF_W   (OFF_N + SZ_N)
#define SZ_W    (1024u*RSIZE)
#define OFF_TH  (OFF_W + SZ_W)
#define SZ_TH   (1024u*64u)
#define OFF_RO  (OFF_TH + SZ_TH)
#define SZ_RO   (512u*64u)
#define OFF_ZK  (OFF_RO + SZ_RO)

// ---------------- K0: exact gelu of rotation weights + 2/n per Householder step
__global__ void k0_gelu(const float* __restrict__ rwh, const float* __restrict__ rwt,
                        float* __restrict__ vg, float* __restrict__ inv2n) {
    int rs = blockIdx.x;               // 0..1023 : side*512 + r
    int side = rs >> 9, r = rs & 511;
    const float* rw = (side ? rwt : rwh) + (size_t)r * 3969;
    __shared__ float vv[DM1 * 65];     // padded stride 65: conflict-free row sums
    int tid = threadIdx.x;             // 64 threads
    for (int idx = tid; idx < 3969; idx += 64) {
        int s = idx / 63, j = idx - s * 63;
        float x = rw[idx];
        float g = 0.5f * x * (1.f + erff(x * 0.70710678118654752f));
        vv[s * 65 + j] = g;
        vg[(size_t)rs * RSIZE + s * WROW + j] = g;
    }
    __syncthreads();
    if (tid < 63) {
        float sum = 0.f;
        #pragma unroll
        for (int j = 0; j < 63; j++) { float v = vv[tid * 65 + j]; sum += v * v; }
        inv2n[rs * 64 + tid] = 2.f / sum;
    }
}

// ---------------- K1: Householder product, one lane = one row of W (rows independent)
__global__ void k1_house(const float* __restrict__ vg, const float* __restrict__ inv2n,
                         float* __restrict__ wg) {
    int rs = blockIdx.x;
    int i = threadIdx.x;               // 64 threads; row i
    if (i >= DM1) return;
    const float* vb = vg + (size_t)rs * RSIZE;
    const float* nb = inv2n + rs * 64;
    float row[DM1];
    #pragma unroll
    for (int j = 0; j < DM1; j++) row[j] = (j == i) ? 1.f : 0.f;
    for (int s = 0; s < DM1; s++) {
        const float* vs = vb + s * WROW;   // wave-uniform address -> scalar loads
        float d0 = 0.f, d1 = 0.f, d2 = 0.f, d3 = 0.f;
        #pragma unroll
        for (int j = 0; j < 60; j += 4) {
            d0 = fmaf(row[j],   vs[j],   d0);
            d1 = fmaf(row[j+1], vs[j+1], d1);
            d2 = fmaf(row[j+2], vs[j+2], d2);
            d3 = fmaf(row[j+3], vs[j+3], d3);
        }
        d0 = fmaf(row[60], vs[60], d0);
        d1 = fmaf(row[61], vs[61], d1);
        d2 = fmaf(row[62], vs[62], d2);
        float dot = (d0 + d1) + (d2 + d3);
        float coef = dot * nb[s];
        #pragma unroll
        for (int j = 0; j < DM1; j++) row[j] = fmaf(-coef, vs[j], row[j]);
    }
    float* wo = wg + (size_t)rs * RSIZE + (size_t)i * WROW;
    #pragma unroll
    for (int j = 0; j < DM1; j++) wo[j] = row[j];
    wo[DM1] = 0.f;                     // zero pad col so 64-wide loops are exact
}

// ---------------- K_ro: tail boost constants per relation
__global__ void k_ro(const float* __restrict__ bwt, float* __restrict__ rog,
                     float* __restrict__ zkg) {
    int r = blockIdx.x, c = threadIdx.x;   // 64 threads
    float rov = (c < 63) ? tanhf(bwt[r * 63 + c]) * 0.015625f : 0.f;
    rog[r * 64 + c] = rov;
    float p = rov * rov;
    #pragma unroll
    for (int off = 32; off; off >>= 1) p += __shfl_xor(p, off);
    if (c == 0) {
        float v2 = p;
        float zeta = 1.f / (sqrtf(1.f - v2) + 1e-8f);
        zkg[r * 2]     = zeta;
        zkg[r * 2 + 1] = (zeta - 1.f) / (v2 + 1e-9f);
    }
}

// ---------------- K2: head transform th[b][0..63] (rotation + boost), lane = out dim
__global__ void k2_th(const int* __restrict__ pos, const float* __restrict__ emb,
                      const float* __restrict__ wg, const float* __restrict__ bwh,
                      float* __restrict__ thg) {
    int b = blockIdx.x, c = threadIdx.x;   // 64 threads
    int u = pos[b * 3], r = pos[b * 3 + 1];
    const float* hrow = emb + (size_t)u * 64;          // wave-uniform -> scalar
    const float* wr = wg + (size_t)r * RSIZE;          // head side (rs = r)
    float xnc = 0.f;
    for (int d = 0; d < DM1; d++) xnc = fmaf(hrow[1 + d], wr[d * WROW + c], xnc);
    float rov = (c < 63) ? tanhf(bwh[r * 63 + c]) * 0.015625f : 0.f;
    float p = rov * rov, q = xnc * rov;
    #pragma unroll
    for (int off = 32; off; off >>= 1) { p += __shfl_xor(p, off); q += __shfl_xor(q, off); }
    float v2 = p, dot = q;
    float zeta = 1.f / (sqrtf(1.f - v2) + 1e-8f);
    float k = (zeta - 1.f) / (v2 + 1e-9f);
    float x0 = hrow[0];
    float val;
    int idx;
    if (c < 63) { val = fmaf(-zeta * x0, rov, xnc) + k * rov * dot; idx = c + 1; }
    else        { val = zeta * x0 - zeta * dot;                      idx = 0;    }
    thg[b * 64 + idx] = val;
}

// ---------------- K3: scoring. block = batch row, thread = tail candidate
__global__ __launch_bounds__(256) void k3_score(
    const int* __restrict__ pos, const int* __restrict__ neg,
    const float* __restrict__ emb, const float* __restrict__ bh,
    const float* __restrict__ bt, const float* __restrict__ wg,
    const float* __restrict__ thg, const float* __restrict__ rog,
    const float* __restrict__ zkg, float* __restrict__ out) {
    int b = blockIdx.x, j = threadIdx.x;
    int u = pos[b * 3], r = pos[b * 3 + 1];
    int v = (j == 0) ? pos[b * 3 + 2] : neg[b * 255 + j - 1];
    const float4* tp4 = (const float4*)(emb + (size_t)v * 64);
    const float* wt = wg + (size_t)(512 + r) * RSIZE;   // tail side
    const float* ro = rog + r * 64;                     // wave-uniform
    const float* th = thg + b * 64;                     // wave-uniform
    float zeta = zkg[2 * r], kk = zkg[2 * r + 1];

    float xn[64];
    #pragma unroll
    for (int c = 0; c < 64; c++) xn[c] = 0.f;
    float x0;
    {   // peel q=0: elements t[0..3] -> x0 and d=0,1,2
        float4 tv = tp4[0];
        x0 = tv.x;
        #pragma unroll
        for (int c = 0; c < 64; c++) xn[c] = fmaf(tv.y, wt[c], xn[c]);
        #pragma unroll
        for (int c = 0; c < 64; c++) xn[c] = fmaf(tv.z, wt[64 + c], xn[c]);
        #pragma unroll
        for (int c = 0; c < 64; c++) xn[c] = fmaf(tv.w, wt[128 + c], xn[c]);
    }
    #pragma unroll 1
    for (int q = 1; q < 16; q++) {      // d = 4q-1 .. 4q+2
        float4 tv = tp4[q];
        const float* wq = wt + (4 * q - 1) * 64;
        #pragma unroll
        for (int c = 0; c < 64; c++) xn[c] = fmaf(tv.x, wq[c], xn[c]);
        #pragma unroll
        for (int c = 0; c < 64; c++) xn[c] = fmaf(tv.y, wq[64 + c], xn[c]);
        #pragma unroll
        for (int c = 0; c < 64; c++) xn[c] = fmaf(tv.z, wq[128 + c], xn[c]);
        #pragma unroll
        for (int c = 0; c < 64; c++) xn[c] = fmaf(tv.w, wq[192 + c], xn[c]);
    }
    // boost(tail) + score. ro[63]=0, xn[63]=0 (W col 63 zeroed).
    float dot = 0.f;
    #pragma unroll
    for (int c = 0; c < 64; c++) dot = fmaf(xn[c], ro[c], dot);
    float tt0 = zeta * x0 - zeta * dot;
    float d0 = tt0 - th[0];
    float acc = -d0 * d0;
    float A = fmaf(kk, dot, -zeta * x0);   // tt[1+c] = xn[c] + A*ro[c]
    #pragma unroll
    for (int c = 0; c < 63; c++) {
        float ttc = fmaf(A, ro[c], xn[c]);
        float dd = ttc - th[1 + c];
        acc = fmaf(dd, dd, acc);
    }
    out[b * 256 + j] = 0.85f - acc + tanhf(bh[u]) + tanhf(bt[v]);
}

extern "C" void kernel_launch(void* const* d_in, const int* in_sizes, int n_in,
                              void* d_out, int out_size, void* d_ws, size_t ws_size,
                              hipStream_t stream) {
    const int*   pos = (const int*)d_in[0];
    const int*   neg = (const int*)d_in[1];
    const float* emb = (const float*)d_in[2];
    const float* bh  = (const float*)d_in[3];
    const float* bt  = (const float*)d_in[4];
    const float* rwh = (const float*)d_in[5];
    const float* bwh = (const float*)d_in[6];
    const float* rwt = (const float*)d_in[7];
    const float* bwt = (const float*)d_in[8];
    float* ws  = (float*)d_ws;
    float* vg  = ws + OFF_V;
    float* nn  = ws + OFF_N;
    float* wgp = ws + OFF_W;
    float* thg = ws + OFF_TH;
    float* rog = ws + OFF_RO;
    float* zkg = ws + OFF_ZK;
    float* out = (float*)d_out;

    k0_gelu <<<dim3(1024), dim3(64),  0, stream>>>(rwh, rwt, vg, nn);
    k1_house<<<dim3(1024), dim3(64),  0, stream>>>(vg, nn, wgp);
    k_ro    <<<dim3(512),  dim3(64),  0, stream>>>(bwt, rog, zkg);
    k2_th   <<<dim3(1024), dim3(64),  0, stream>>>(pos, emb, wgp, bwh, thg);
    k3_score<<<dim3(1024), dim3(256), 0, stream>>>(pos, neg, emb, bh, bt, wgp,
                                                   thg, rog, zkg, out);
}

// Round 2
// 166.569 us; speedup vs baseline: 1.0922x; 1.0922x over previous
//
#include <hip/hip_runtime.h>
#include <math.h>

#define DM1 63
#define WROW 64
#define RSIZE (DM1*WROW)   // 4032 floats per rel-side matrix / gelu-v block

typedef float f4 __attribute__((ext_vector_type(4)));

// d_ws float offsets
#define OFF_V   0u
#define SZ_V    (1024u*RSIZE)
#define OFF_N   (OFF_V + SZ_V)
#define SZ_N    (1024u*64u)
#define OFF_W   (OFF_N + SZ_N)
#define SZ_W    (1024u*RSIZE)
#define OFF_TH  (OFF_W + SZ_W)
#define SZ_TH   (1024u*64u)
#define OFF_RO  (OFF_TH + SZ_TH)
#define SZ_RO   (512u*64u)
#define OFF_ZK  (OFF_RO + SZ_RO)

// ---------------- K0: exact gelu of rotation weights + 2/n per Householder step
__global__ void k0_gelu(const float* __restrict__ rwh, const float* __restrict__ rwt,
                        float* __restrict__ vg, float* __restrict__ inv2n) {
    int rs = blockIdx.x;               // 0..1023 : side*512 + r
    int side = rs >> 9, r = rs & 511;
    const float* rw = (side ? rwt : rwh) + (size_t)r * 3969;
    __shared__ float vv[DM1 * 65];     // padded stride 65: conflict-free row sums
    int tid = threadIdx.x;             // 64 threads
    for (int idx = tid; idx < 3969; idx += 64) {
        int s = idx / 63, j = idx - s * 63;
        float x = rw[idx];
        float g = 0.5f * x * (1.f + erff(x * 0.70710678118654752f));
        vv[s * 65 + j] = g;
        vg[(size_t)rs * RSIZE + s * WROW + j] = g;
    }
    if (tid < 63) vg[(size_t)rs * RSIZE + tid * WROW + DM1] = 0.f;  // zero pad col
    __syncthreads();
    if (tid < 63) {
        float sum = 0.f;
        #pragma unroll
        for (int j = 0; j < 63; j++) { float v = vv[tid * 65 + j]; sum += v * v; }
        inv2n[rs * 64 + tid] = 2.f / sum;
    }
}

// ---------------- K1: Householder product, one lane = one row of W (rows independent)
// Row state in 16 NAMED float4 registers (no arrays -> no scratch). v-step data
// double-buffered in two named 16xfloat4 register sets (global loads overlap FMAs).
#define LOADV(V, s) do { const f4* _vp = (const f4*)(vb + (size_t)(s) * WROW); \
    V##0=_vp[0];  V##1=_vp[1];  V##2=_vp[2];  V##3=_vp[3]; \
    V##4=_vp[4];  V##5=_vp[5];  V##6=_vp[6];  V##7=_vp[7]; \
    V##8=_vp[8];  V##9=_vp[9];  V##10=_vp[10];V##11=_vp[11]; \
    V##12=_vp[12];V##13=_vp[13];V##14=_vp[14];V##15=_vp[15]; } while(0)

#define STEP(V, s) do { \
    f4 c0 = r0*V##0;  c0 += r4*V##4;  c0 += r8*V##8;   c0 += r12*V##12; \
    f4 c1 = r1*V##1;  c1 += r5*V##5;  c1 += r9*V##9;   c1 += r13*V##13; \
    f4 c2 = r2*V##2;  c2 += r6*V##6;  c2 += r10*V##10; c2 += r14*V##14; \
    f4 c3 = r3*V##3;  c3 += r7*V##7;  c3 += r11*V##11; c3 += r15*V##15; \
    f4 cs = (c0 + c1) + (c2 + c3); \
    float dot = (cs[0] + cs[1]) + (cs[2] + cs[3]); \
    float cf = dot * nb[s]; \
    r0  -= cf*V##0;  r1  -= cf*V##1;  r2  -= cf*V##2;  r3  -= cf*V##3; \
    r4  -= cf*V##4;  r5  -= cf*V##5;  r6  -= cf*V##6;  r7  -= cf*V##7; \
    r8  -= cf*V##8;  r9  -= cf*V##9;  r10 -= cf*V##10; r11 -= cf*V##11; \
    r12 -= cf*V##12; r13 -= cf*V##13; r14 -= cf*V##14; r15 -= cf*V##15; } while(0)

#define INITR(k) do { \
    r##k[0] = (i == 4*(k)+0) ? 1.f : 0.f; \
    r##k[1] = (i == 4*(k)+1) ? 1.f : 0.f; \
    r##k[2] = (i == 4*(k)+2) ? 1.f : 0.f; \
    r##k[3] = (i == 4*(k)+3) ? 1.f : 0.f; } while(0)

__global__ void k1_house(const float* __restrict__ vg, const float* __restrict__ inv2n,
                         float* __restrict__ wg) {
    int rs = blockIdx.x;
    int i = threadIdx.x;               // 64 lanes; lane 63 computes a zero dummy row
    const float* vb = vg + (size_t)rs * RSIZE;
    const float* nb = inv2n + rs * 64;
    f4 r0,r1,r2,r3,r4,r5,r6,r7,r8,r9,r10,r11,r12,r13,r14,r15;
    f4 aa0,aa1,aa2,aa3,aa4,aa5,aa6,aa7,aa8,aa9,aa10,aa11,aa12,aa13,aa14,aa15;
    f4 bb0,bb1,bb2,bb3,bb4,bb5,bb6,bb7,bb8,bb9,bb10,bb11,bb12,bb13,bb14,bb15;
    INITR(0); INITR(1); INITR(2); INITR(3); INITR(4); INITR(5); INITR(6); INITR(7);
    INITR(8); INITR(9); INITR(10);INITR(11);INITR(12);INITR(13);INITR(14);INITR(15);
    if (i == DM1) { r15[3] = 0.f; }    // lane 63: all-zero row (stays zero: dot=0)

    LOADV(aa, 0);
    #pragma unroll 1
    for (int s = 0; s < 62; s += 2) {
        LOADV(bb, s + 1);
        STEP(aa, s);
        LOADV(aa, s + 2);
        STEP(bb, s + 1);
    }
    STEP(aa, 62);

    if (i < DM1) {
        r15[3] = 0.f;                  // pad col stays exactly 0
        f4* wo = (f4*)(wg + (size_t)rs * RSIZE + (size_t)i * WROW);
        wo[0]=r0;  wo[1]=r1;  wo[2]=r2;  wo[3]=r3;
        wo[4]=r4;  wo[5]=r5;  wo[6]=r6;  wo[7]=r7;
        wo[8]=r8;  wo[9]=r9;  wo[10]=r10;wo[11]=r11;
        wo[12]=r12;wo[13]=r13;wo[14]=r14;wo[15]=r15;
    }
}

// ---------------- K_ro: tail boost constants per relation
__global__ void k_ro(const float* __restrict__ bwt, float* __restrict__ rog,
                     float* __restrict__ zkg) {
    int r = blockIdx.x, c = threadIdx.x;   // 64 threads
    float rov = (c < 63) ? tanhf(bwt[r * 63 + c]) * 0.015625f : 0.f;
    rog[r * 64 + c] = rov;
    float p = rov * rov;
    #pragma unroll
    for (int off = 32; off; off >>= 1) p += __shfl_xor(p, off);
    if (c == 0) {
        float v2 = p;
        float zeta = 1.f / (sqrtf(1.f - v2) + 1e-8f);
        zkg[r * 2]     = zeta;
        zkg[r * 2 + 1] = (zeta - 1.f) / (v2 + 1e-9f);
    }
}

// ---------------- K2: head transform th[b][0..63] (rotation + boost), lane = out dim
__global__ void k2_th(const int* __restrict__ pos, const float* __restrict__ emb,
                      const float* __restrict__ wg, const float* __restrict__ bwh,
                      float* __restrict__ thg) {
    int b = blockIdx.x, c = threadIdx.x;   // 64 threads
    int u = pos[b * 3], r = pos[b * 3 + 1];
    const float* hrow = emb + (size_t)u * 64;          // wave-uniform -> scalar
    const float* wr = wg + (size_t)r * RSIZE;          // head side (rs = r)
    float xnc = 0.f;
    for (int d = 0; d < DM1; d++) xnc = fmaf(hrow[1 + d], wr[d * WROW + c], xnc);
    float rov = (c < 63) ? tanhf(bwh[r * 63 + c]) * 0.015625f : 0.f;
    float p = rov * rov, q = xnc * rov;
    #pragma unroll
    for (int off = 32; off; off >>= 1) { p += __shfl_xor(p, off); q += __shfl_xor(q, off); }
    float v2 = p, dot = q;
    float zeta = 1.f / (sqrtf(1.f - v2) + 1e-8f);
    float k = (zeta - 1.f) / (v2 + 1e-9f);
    float x0 = hrow[0];
    float val;
    int idx;
    if (c < 63) { val = fmaf(-zeta * x0, rov, xnc) + k * rov * dot; idx = c + 1; }
    else        { val = zeta * x0 - zeta * dot;                      idx = 0;    }
    thg[b * 64 + idx] = val;
}

// ---------------- K3: scoring. block = batch row, thread = tail candidate
__global__ __launch_bounds__(256) void k3_score(
    const int* __restrict__ pos, const int* __restrict__ neg,
    const float* __restrict__ emb, const float* __restrict__ bh,
    const float* __restrict__ bt, const float* __restrict__ wg,
    const float* __restrict__ thg, const float* __restrict__ rog,
    const float* __restrict__ zkg, float* __restrict__ out) {
    int b = blockIdx.x, j = threadIdx.x;
    int u = pos[b * 3], r = pos[b * 3 + 1];
    int v = (j == 0) ? pos[b * 3 + 2] : neg[b * 255 + j - 1];
    const float4* tp4 = (const float4*)(emb + (size_t)v * 64);
    const float* wt = wg + (size_t)(512 + r) * RSIZE;   // tail side
    const float* ro = rog + r * 64;                     // wave-uniform
    const float* th = thg + b * 64;                     // wave-uniform
    float zeta = zkg[2 * r], kk = zkg[2 * r + 1];

    float xn[64];
    #pragma unroll
    for (int c = 0; c < 64; c++) xn[c] = 0.f;
    float x0;
    {   // peel q=0: elements t[0..3] -> x0 and d=0,1,2
        float4 tv = tp4[0];
        x0 = tv.x;
        #pragma unroll
        for (int c = 0; c < 64; c++) xn[c] = fmaf(tv.y, wt[c], xn[c]);
        #pragma unroll
        for (int c = 0; c < 64; c++) xn[c] = fmaf(tv.z, wt[64 + c], xn[c]);
        #pragma unroll
        for (int c = 0; c < 64; c++) xn[c] = fmaf(tv.w, wt[128 + c], xn[c]);
    }
    #pragma unroll 1
    for (int q = 1; q < 16; q++) {      // d = 4q-1 .. 4q+2
        float4 tv = tp4[q];
        const float* wq = wt + (4 * q - 1) * 64;
        #pragma unroll
        for (int c = 0; c < 64; c++) xn[c] = fmaf(tv.x, wq[c], xn[c]);
        #pragma unroll
        for (int c = 0; c < 64; c++) xn[c] = fmaf(tv.y, wq[64 + c], xn[c]);
        #pragma unroll
        for (int c = 0; c < 64; c++) xn[c] = fmaf(tv.z, wq[128 + c], xn[c]);
        #pragma unroll
        for (int c = 0; c < 64; c++) xn[c] = fmaf(tv.w, wq[192 + c], xn[c]);
    }
    // boost(tail) + score. ro[63]=0, xn[63]=0 (W col 63 zeroed).
    float dot = 0.f;
    #pragma unroll
    for (int c = 0; c < 64; c++) dot = fmaf(xn[c], ro[c], dot);
    float tt0 = zeta * x0 - zeta * dot;
    float d0 = tt0 - th[0];
    float acc = -d0 * d0;
    float A = fmaf(kk, dot, -zeta * x0);   // tt[1+c] = xn[c] + A*ro[c]
    #pragma unroll
    for (int c = 0; c < 63; c++) {
        float ttc = fmaf(A, ro[c], xn[c]);
        float dd = ttc - th[1 + c];
        acc = fmaf(dd, dd, acc);
    }
    out[b * 256 + j] = 0.85f - acc + tanhf(bh[u]) + tanhf(bt[v]);
}

extern "C" void kernel_launch(void* const* d_in, const int* in_sizes, int n_in,
                              void* d_out, int out_size, void* d_ws, size_t ws_size,
                              hipStream_t stream) {
    const int*   pos = (const int*)d_in[0];
    const int*   neg = (const int*)d_in[1];
    const float* emb = (const float*)d_in[2];
    const float* bh  = (const float*)d_in[3];
    const float* bt  = (const float*)d_in[4];
    const float* rwh = (const float*)d_in[5];
    const float* bwh = (const float*)d_in[6];
    const float* rwt = (const float*)d_in[7];
    const float* bwt = (const float*)d_in[8];
    float* ws  = (float*)d_ws;
    float* vg  = ws + OFF_V;
    float* nn  = ws + OFF_N;
    float* wgp = ws + OFF_W;
    float* thg = ws + OFF_TH;
    float* rog = ws + OFF_RO;
    float* zkg = ws + OFF_ZK;
    float* out = (float*)d_out;

    k0_gelu <<<dim3(1024), dim3(64),  0, stream>>>(rwh, rwt, vg, nn);
    k1_house<<<dim3(1024), dim3(64),  0, stream>>>(vg, nn, wgp);
    k_ro    <<<dim3(512),  dim3(64),  0, stream>>>(bwt, rog, zkg);
    k2_th   <<<dim3(1024), dim3(64),  0, stream>>>(pos, emb, wgp, bwh, thg);
    k3_score<<<dim3(1024), dim3(256), 0, stream>>>(pos, neg, emb, bh, bt, wgp,
                                                   thg, rog, zkg, out);
}

// Round 3
// 134.411 us; speedup vs baseline: 1.3535x; 1.2393x over previous
//
#include <hip/hip_runtime.h>
#include <math.h>

#define DM1 63
#define WROW 64
#define RSIZE (DM1*WROW)   // 4032 floats per rel-side matrix

typedef float f4 __attribute__((ext_vector_type(4)));

// d_ws float offsets
#define OFF_V   0u
#define SZ_V    (1024u*RSIZE)
#define OFF_W   (OFF_V + SZ_V)
#define SZ_W    (1024u*RSIZE)
#define OFF_TH  (OFF_W + SZ_W)
#define SZ_TH   (1024u*64u)
#define OFF_RO  (OFF_TH + SZ_TH)
#define SZ_RO   (512u*64u)
#define OFF_ZK  (OFF_RO + SZ_RO)

// ---------------- K0: exact gelu of rotation weights, pre-scaled by sqrt(2/n).
// With v' = v*sqrt(2/n), the Householder step is row -= (row.v')*v'.
__global__ __launch_bounds__(256) void k0_gelu(const float* __restrict__ rwh,
                                               const float* __restrict__ rwt,
                                               float* __restrict__ vg) {
    int rs = blockIdx.x;               // 0..1023 : side*512 + r
    int side = rs >> 9, r = rs & 511;
    const float* rw = (side ? rwt : rwh) + (size_t)r * 3969;
    __shared__ float vv[DM1 * 65];     // padded stride 65: conflict-free row sums
    __shared__ float sc[DM1];
    int tid = threadIdx.x;             // 256 threads
    for (int idx = tid; idx < 3969; idx += 256) {
        int s = idx / 63, j = idx - s * 63;
        float x = rw[idx];
        vv[s * 65 + j] = 0.5f * x * (1.f + erff(x * 0.70710678118654752f));
    }
    __syncthreads();
    if (tid < DM1) {
        float sum = 0.f;
        #pragma unroll
        for (int j = 0; j < 63; j++) { float v = vv[tid * 65 + j]; sum += v * v; }
        sc[tid] = sqrtf(2.f / sum);
    }
    __syncthreads();
    float* vo = vg + (size_t)rs * RSIZE;
    for (int idx = tid; idx < 3969; idx += 256) {
        int s = idx / 63, j = idx - s * 63;
        vo[s * WROW + j] = vv[s * 65 + j] * sc[s];
    }
    if (tid < DM1) vo[tid * WROW + DM1] = 0.f;   // zero pad col 63
}

// ---------------- K1: Householder product. 4 lanes per row, 16 cols per lane.
// State: 4 f4 per lane. v-slice double-buffered in 2x4 f4. ~56 VGPRs total.
#define K1LOAD(V, s) do { const f4* _vp = (const f4*)(vbase + (size_t)(s) * WROW); \
    V##0 = _vp[0]; V##1 = _vp[1]; V##2 = _vp[2]; V##3 = _vp[3]; } while(0)

#define K1STEP(V) do { \
    f4 q01 = w0*V##0 + w1*V##1; \
    f4 q23 = w2*V##2 + w3*V##3; \
    f4 q = q01 + q23; \
    float d = (q[0] + q[1]) + (q[2] + q[3]); \
    d += __shfl_xor(d, 1); \
    d += __shfl_xor(d, 2); \
    w0 -= d*V##0; w1 -= d*V##1; w2 -= d*V##2; w3 -= d*V##3; } while(0)

__global__ __launch_bounds__(256) void k1_house(const float* __restrict__ vg,
                                                float* __restrict__ wg) {
    int rs = blockIdx.x;
    int tid = threadIdx.x;
    int lane = tid & 63, wv = tid >> 6;
    int row = wv * 16 + (lane >> 2);   // 0..63 (row 63 is a dummy)
    int p = lane & 3;                  // column quarter
    int c0 = p * 16;
    const float* vbase = vg + (size_t)rs * RSIZE + c0;

    f4 w0, w1, w2, w3;
    #define IW(k, b) (((b) + (k)) == row ? 1.f : 0.f)
    w0 = (f4){IW(0,c0),    IW(1,c0),    IW(2,c0),    IW(3,c0)};
    w1 = (f4){IW(0,c0+4),  IW(1,c0+4),  IW(2,c0+4),  IW(3,c0+4)};
    w2 = (f4){IW(0,c0+8),  IW(1,c0+8),  IW(2,c0+8),  IW(3,c0+8)};
    w3 = (f4){IW(0,c0+12), IW(1,c0+12), IW(2,c0+12), IW(3,c0+12)};
    #undef IW

    f4 a0, a1, a2, a3, b0, b1, b2, b3;
    K1LOAD(a, 0);
    #pragma unroll 1
    for (int s = 0; s < 62; s += 2) {
        K1LOAD(b, s + 1);
        K1STEP(a);
        K1LOAD(a, s + 2);
        K1STEP(b);
    }
    K1STEP(a);                          // s = 62

    if (row < DM1) {
        f4* wo = (f4*)(wg + (size_t)rs * RSIZE + (size_t)row * WROW + c0);
        wo[0] = w0; wo[1] = w1; wo[2] = w2; wo[3] = w3;
    }
}

// ---------------- K_ro: tail boost constants per relation
__global__ void k_ro(const float* __restrict__ bwt, float* __restrict__ rog,
                     float* __restrict__ zkg) {
    int r = blockIdx.x, c = threadIdx.x;   // 64 threads
    float rov = (c < 63) ? tanhf(bwt[r * 63 + c]) * 0.015625f : 0.f;
    rog[r * 64 + c] = rov;
    float p = rov * rov;
    #pragma unroll
    for (int off = 32; off; off >>= 1) p += __shfl_xor(p, off);
    if (c == 0) {
        float v2 = p;
        float zeta = 1.f / (sqrtf(1.f - v2) + 1e-8f);
        zkg[r * 2]     = zeta;
        zkg[r * 2 + 1] = (zeta - 1.f) / (v2 + 1e-9f);
    }
}

// ---------------- K2: head transform th[b][0..63] (rotation + boost), lane = out dim
__global__ void k2_th(const int* __restrict__ pos, const float* __restrict__ emb,
                      const float* __restrict__ wg, const float* __restrict__ bwh,
                      float* __restrict__ thg) {
    int b = blockIdx.x, c = threadIdx.x;   // 64 threads
    int u = pos[b * 3], r = pos[b * 3 + 1];
    const float* hrow = emb + (size_t)u * 64;          // wave-uniform -> scalar
    const float* wr = wg + (size_t)r * RSIZE;          // head side (rs = r)
    float xnc = 0.f;
    for (int d = 0; d < DM1; d++) xnc = fmaf(hrow[1 + d], wr[d * WROW + c], xnc);
    float rov = (c < 63) ? tanhf(bwh[r * 63 + c]) * 0.015625f : 0.f;
    float p = rov * rov, q = xnc * rov;
    #pragma unroll
    for (int off = 32; off; off >>= 1) { p += __shfl_xor(p, off); q += __shfl_xor(q, off); }
    float v2 = p, dot = q;
    float zeta = 1.f / (sqrtf(1.f - v2) + 1e-8f);
    float k = (zeta - 1.f) / (v2 + 1e-9f);
    float x0 = hrow[0];
    float val;
    int idx;
    if (c < 63) { val = fmaf(-zeta * x0, rov, xnc) + k * rov * dot; idx = c + 1; }
    else        { val = zeta * x0 - zeta * dot;                      idx = 0;    }
    thg[b * 64 + idx] = val;
}

// ---------------- K3: scoring. block = batch row, thread = tail candidate
__global__ __launch_bounds__(256) void k3_score(
    const int* __restrict__ pos, const int* __restrict__ neg,
    const float* __restrict__ emb, const float* __restrict__ bh,
    const float* __restrict__ bt, const float* __restrict__ wg,
    const float* __restrict__ thg, const float* __restrict__ rog,
    const float* __restrict__ zkg, float* __restrict__ out) {
    int b = blockIdx.x, j = threadIdx.x;
    int u = pos[b * 3], r = pos[b * 3 + 1];
    int v = (j == 0) ? pos[b * 3 + 2] : neg[b * 255 + j - 1];
    const float4* tp4 = (const float4*)(emb + (size_t)v * 64);
    const float* wt = wg + (size_t)(512 + r) * RSIZE;   // tail side
    const float* ro = rog + r * 64;                     // wave-uniform
    const float* th = thg + b * 64;                     // wave-uniform
    float zeta = zkg[2 * r], kk = zkg[2 * r + 1];

    float xn[64];
    #pragma unroll
    for (int c = 0; c < 64; c++) xn[c] = 0.f;
    float x0;
    {   // peel q=0: elements t[0..3] -> x0 and d=0,1,2
        float4 tv = tp4[0];
        x0 = tv.x;
        #pragma unroll
        for (int c = 0; c < 64; c++) xn[c] = fmaf(tv.y, wt[c], xn[c]);
        #pragma unroll
        for (int c = 0; c < 64; c++) xn[c] = fmaf(tv.z, wt[64 + c], xn[c]);
        #pragma unroll
        for (int c = 0; c < 64; c++) xn[c] = fmaf(tv.w, wt[128 + c], xn[c]);
    }
    #pragma unroll 1
    for (int q = 1; q < 16; q++) {      // d = 4q-1 .. 4q+2
        float4 tv = tp4[q];
        const float* wq = wt + (4 * q - 1) * 64;
        #pragma unroll
        for (int c = 0; c < 64; c++) xn[c] = fmaf(tv.x, wq[c], xn[c]);
        #pragma unroll
        for (int c = 0; c < 64; c++) xn[c] = fmaf(tv.y, wq[64 + c], xn[c]);
        #pragma unroll
        for (int c = 0; c < 64; c++) xn[c] = fmaf(tv.z, wq[128 + c], xn[c]);
        #pragma unroll
        for (int c = 0; c < 64; c++) xn[c] = fmaf(tv.w, wq[192 + c], xn[c]);
    }
    // boost(tail) + score. ro[63]=0, xn[63]=0 (W col 63 zeroed).
    float dot = 0.f;
    #pragma unroll
    for (int c = 0; c < 64; c++) dot = fmaf(xn[c], ro[c], dot);
    float tt0 = zeta * x0 - zeta * dot;
    float d0 = tt0 - th[0];
    float acc = -d0 * d0;
    float A = fmaf(kk, dot, -zeta * x0);   // tt[1+c] = xn[c] + A*ro[c]
    #pragma unroll
    for (int c = 0; c < 63; c++) {
        float ttc = fmaf(A, ro[c], xn[c]);
        float dd = ttc - th[1 + c];
        acc = fmaf(dd, dd, acc);
    }
    out[b * 256 + j] = 0.85f - acc + tanhf(bh[u]) + tanhf(bt[v]);
}

extern "C" void kernel_launch(void* const* d_in, const int* in_sizes, int n_in,
                              void* d_out, int out_size, void* d_ws, size_t ws_size,
                              hipStream_t stream) {
    const int*   pos = (const int*)d_in[0];
    const int*   neg = (const int*)d_in[1];
    const float* emb = (const float*)d_in[2];
    const float* bh  = (const float*)d_in[3];
    const float* bt  = (const float*)d_in[4];
    const float* rwh = (const float*)d_in[5];
    const float* bwh = (const float*)d_in[6];
    const float* rwt = (const float*)d_in[7];
    const float* bwt = (const float*)d_in[8];
    float* ws  = (float*)d_ws;
    float* vg  = ws + OFF_V;
    float* wgp = ws + OFF_W;
    float* thg = ws + OFF_TH;
    float* rog = ws + OFF_RO;
    float* zkg = ws + OFF_ZK;
    float* out = (float*)d_out;

    k0_gelu <<<dim3(1024), dim3(256), 0, stream>>>(rwh, rwt, vg);
    k1_house<<<dim3(1024), dim3(256), 0, stream>>>(vg, wgp);
    k_ro    <<<dim3(512),  dim3(64),  0, stream>>>(bwt, rog, zkg);
    k2_th   <<<dim3(1024), dim3(64),  0, stream>>>(pos, emb, wgp, bwh, thg);
    k3_score<<<dim3(1024), dim3(256), 0, stream>>>(pos, neg, emb, bh, bt, wgp,
                                                   thg, rog, zkg, out);
}

// Round 5
// 134.141 us; speedup vs baseline: 1.3562x; 1.0020x over previous
//
#include <hip/hip_runtime.h>
#include <math.h>

#define DM1 63
#define WROW 64
#define RSIZE (DM1*WROW)   // 4032 floats per rel-side matrix

typedef float f4 __attribute__((ext_vector_type(4)));

// d_ws float offsets
#define OFF_V   0u
#define SZ_V    (1024u*RSIZE)
#define OFF_W   (OFF_V + SZ_V)
#define SZ_W    (1024u*RSIZE)
#define OFF_TH  (OFF_W + SZ_W)
#define SZ_TH   (1024u*64u)
#define OFF_RO  (OFF_TH + SZ_TH)
#define SZ_RO   (512u*64u)
#define OFF_ZK  (OFF_RO + SZ_RO)

// ---------------- K0: exact gelu of rotation weights, pre-scaled by sqrt(2/n).
// With v' = v*sqrt(2/n), the Householder step is row -= (row.v')*v'.
__global__ __launch_bounds__(256) void k0_gelu(const float* __restrict__ rwh,
                                               const float* __restrict__ rwt,
                                               float* __restrict__ vg) {
    int rs = blockIdx.x;               // 0..1023 : side*512 + r
    int side = rs >> 9, r = rs & 511;
    const float* rw = (side ? rwt : rwh) + (size_t)r * 3969;
    __shared__ float vv[DM1 * 65];     // padded stride 65: conflict-free row sums
    __shared__ float sc[DM1];
    int tid = threadIdx.x;             // 256 threads
    for (int idx = tid; idx < 3969; idx += 256) {
        int s = idx / 63, j = idx - s * 63;
        float x = rw[idx];
        vv[s * 65 + j] = 0.5f * x * (1.f + erff(x * 0.70710678118654752f));
    }
    __syncthreads();
    if (tid < DM1) {
        float sum = 0.f;
        #pragma unroll
        for (int j = 0; j < 63; j++) { float v = vv[tid * 65 + j]; sum += v * v; }
        sc[tid] = sqrtf(2.f / sum);
    }
    __syncthreads();
    float* vo = vg + (size_t)rs * RSIZE;
    for (int idx = tid; idx < 3969; idx += 256) {
        int s = idx / 63, j = idx - s * 63;
        vo[s * WROW + j] = vv[s * 65 + j] * sc[s];
    }
    if (tid < DM1) vo[tid * WROW + DM1] = 0.f;   // zero pad col 63
}

// ---------------- K1: Householder product. 4 lanes per row, 16 cols per lane.
// Quad reduce via DPP quad_perm (VALU, ~4cy) instead of ds_swizzle (~100cy).
// v-slices prefetched 4 deep (3 steps ahead) to cover cold-HBM latency.
__device__ __forceinline__ float qreduce(float d) {
#if __has_builtin(__builtin_amdgcn_mov_dpp)
    int t = __builtin_amdgcn_mov_dpp(__float_as_int(d), 0xB1, 0xF, 0xF, true); // xor1
    d += __int_as_float(t);
    t = __builtin_amdgcn_mov_dpp(__float_as_int(d), 0x4E, 0xF, 0xF, true);     // xor2
    d += __int_as_float(t);
    return d;
#else
    d += __shfl_xor(d, 1);
    d += __shfl_xor(d, 2);
    return d;
#endif
}

#define K1LOAD(V, s) do { const f4* _vp = (const f4*)(vbase + (size_t)(s) * WROW); \
    V##0 = _vp[0]; V##1 = _vp[1]; V##2 = _vp[2]; V##3 = _vp[3]; } while(0)

#define K1STEP(V) do { \
    f4 q01 = w0*V##0 + w1*V##1; \
    f4 q23 = w2*V##2 + w3*V##3; \
    f4 q = q01 + q23; \
    float d = (q[0] + q[1]) + (q[2] + q[3]); \
    d = qreduce(d); \
    w0 -= d*V##0; w1 -= d*V##1; w2 -= d*V##2; w3 -= d*V##3; } while(0)

__global__ __launch_bounds__(256) void k1_house(const float* __restrict__ vg,
                                                float* __restrict__ wg) {
    int rs = blockIdx.x;
    int tid = threadIdx.x;
    int lane = tid & 63, wv = tid >> 6;
    int row = wv * 16 + (lane >> 2);   // 0..63 (row 63 is a dummy)
    int p = lane & 3;                  // column quarter
    int c0 = p * 16;
    const float* vbase = vg + (size_t)rs * RSIZE + c0;

    f4 w0, w1, w2, w3;
    #define IW(k, b) (((b) + (k)) == row ? 1.f : 0.f)
    w0 = (f4){IW(0,c0),    IW(1,c0),    IW(2,c0),    IW(3,c0)};
    w1 = (f4){IW(0,c0+4),  IW(1,c0+4),  IW(2,c0+4),  IW(3,c0+4)};
    w2 = (f4){IW(0,c0+8),  IW(1,c0+8),  IW(2,c0+8),  IW(3,c0+8)};
    w3 = (f4){IW(0,c0+12), IW(1,c0+12), IW(2,c0+12), IW(3,c0+12)};
    #undef IW

    f4 va0,va1,va2,va3, vb0,vb1,vb2,vb3, vc0,vc1,vc2,vc3, vd0,vd1,vd2,vd3;
    K1LOAD(va, 0); K1LOAD(vb, 1); K1LOAD(vc, 2); K1LOAD(vd, 3);
    #pragma unroll 1
    for (int s = 0; s < 56; s += 4) {
        K1STEP(va); K1LOAD(va, s + 4);
        K1STEP(vb); K1LOAD(vb, s + 5);
        K1STEP(vc); K1LOAD(vc, s + 6);
        K1STEP(vd); K1LOAD(vd, s + 7);
    }
    K1STEP(va); K1LOAD(va, 60);  // s=56
    K1STEP(vb); K1LOAD(vb, 61);  // s=57
    K1STEP(vc); K1LOAD(vc, 62);  // s=58
    K1STEP(vd);                  // s=59
    K1STEP(va);                  // s=60
    K1STEP(vb);                  // s=61
    K1STEP(vc);                  // s=62

    if (row < DM1) {
        f4* wo = (f4*)(wg + (size_t)rs * RSIZE + (size_t)row * WROW + c0);
        wo[0] = w0; wo[1] = w1; wo[2] = w2; wo[3] = w3;
    }
}

// ---------------- K_ro: tail boost constants per relation
__global__ void k_ro(const float* __restrict__ bwt, float* __restrict__ rog,
                     float* __restrict__ zkg) {
    int r = blockIdx.x, c = threadIdx.x;   // 64 threads
    float rov = (c < 63) ? tanhf(bwt[r * 63 + c]) * 0.015625f : 0.f;
    rog[r * 64 + c] = rov;
    float p = rov * rov;
    #pragma unroll
    for (int off = 32; off; off >>= 1) p += __shfl_xor(p, off);
    if (c == 0) {
        float v2 = p;
        float zeta = 1.f / (sqrtf(1.f - v2) + 1e-8f);
        zkg[r * 2]     = zeta;
        zkg[r * 2 + 1] = (zeta - 1.f) / (v2 + 1e-9f);
    }
}

// ---------------- K2: head transform th[b][0..63] (rotation + boost), lane = out dim
__global__ void k2_th(const int* __restrict__ pos, const float* __restrict__ emb,
                      const float* __restrict__ wg, const float* __restrict__ bwh,
                      float* __restrict__ thg) {
    int b = blockIdx.x, c = threadIdx.x;   // 64 threads
    int u = pos[b * 3], r = pos[b * 3 + 1];
    const float* hrow = emb + (size_t)u * 64;          // wave-uniform -> scalar
    const float* wr = wg + (size_t)r * RSIZE;          // head side (rs = r)
    float xnc = 0.f;
    for (int d = 0; d < DM1; d++) xnc = fmaf(hrow[1 + d], wr[d * WROW + c], xnc);
    float rov = (c < 63) ? tanhf(bwh[r * 63 + c]) * 0.015625f : 0.f;
    float p = rov * rov, q = xnc * rov;
    #pragma unroll
    for (int off = 32; off; off >>= 1) { p += __shfl_xor(p, off); q += __shfl_xor(q, off); }
    float v2 = p, dot = q;
    float zeta = 1.f / (sqrtf(1.f - v2) + 1e-8f);
    float k = (zeta - 1.f) / (v2 + 1e-9f);
    float x0 = hrow[0];
    float val;
    int idx;
    if (c < 63) { val = fmaf(-zeta * x0, rov, xnc) + k * rov * dot; idx = c + 1; }
    else        { val = zeta * x0 - zeta * dot;                      idx = 0;    }
    thg[b * 64 + idx] = val;
}

// ---------------- K3: scoring. block = batch row, thread = tail candidate
__global__ __launch_bounds__(256) void k3_score(
    const int* __restrict__ pos, const int* __restrict__ neg,
    const float* __restrict__ emb, const float* __restrict__ bh,
    const float* __restrict__ bt, const float* __restrict__ wg,
    const float* __restrict__ thg, const float* __restrict__ rog,
    const float* __restrict__ zkg, float* __restrict__ out) {
    int b = blockIdx.x, j = threadIdx.x;
    int u = pos[b * 3], r = pos[b * 3 + 1];
    int v = (j == 0) ? pos[b * 3 + 2] : neg[b * 255 + j - 1];
    const float4* tp4 = (const float4*)(emb + (size_t)v * 64);
    const float* wt = wg + (size_t)(512 + r) * RSIZE;   // tail side
    const float* ro = rog + r * 64;                     // wave-uniform
    const float* th = thg + b * 64;                     // wave-uniform
    float zeta = zkg[2 * r], kk = zkg[2 * r + 1];

    float xn[64];
    #pragma unroll
    for (int c = 0; c < 64; c++) xn[c] = 0.f;
    float x0;
    {   // peel q=0: elements t[0..3] -> x0 and d=0,1,2
        float4 tv = tp4[0];
        x0 = tv.x;
        #pragma unroll
        for (int c = 0; c < 64; c++) xn[c] = fmaf(tv.y, wt[c], xn[c]);
        #pragma unroll
        for (int c = 0; c < 64; c++) xn[c] = fmaf(tv.z, wt[64 + c], xn[c]);
        #pragma unroll
        for (int c = 0; c < 64; c++) xn[c] = fmaf(tv.w, wt[128 + c], xn[c]);
    }
    #pragma unroll 1
    for (int q = 1; q < 16; q++) {      // d = 4q-1 .. 4q+2
        float4 tv = tp4[q];
        const float* wq = wt + (4 * q - 1) * 64;
        #pragma unroll
        for (int c = 0; c < 64; c++) xn[c] = fmaf(tv.x, wq[c], xn[c]);
        #pragma unroll
        for (int c = 0; c < 64; c++) xn[c] = fmaf(tv.y, wq[64 + c], xn[c]);
        #pragma unroll
        for (int c = 0; c < 64; c++) xn[c] = fmaf(tv.z, wq[128 + c], xn[c]);
        #pragma unroll
        for (int c = 0; c < 64; c++) xn[c] = fmaf(tv.w, wq[192 + c], xn[c]);
    }
    // boost(tail) + score. ro[63]=0, xn[63]=0 (W col 63 zeroed).
    float dot = 0.f;
    #pragma unroll
    for (int c = 0; c < 64; c++) dot = fmaf(xn[c], ro[c], dot);
    float tt0 = zeta * x0 - zeta * dot;
    float d0 = tt0 - th[0];
    float acc = -d0 * d0;
    float A = fmaf(kk, dot, -zeta * x0);   // tt[1+c] = xn[c] + A*ro[c]
    #pragma unroll
    for (int c = 0; c < 63; c++) {
        float ttc = fmaf(A, ro[c], xn[c]);
        float dd = ttc - th[1 + c];
        acc = fmaf(dd, dd, acc);
    }
    out[b * 256 + j] = 0.85f - acc + tanhf(bh[u]) + tanhf(bt[v]);
}

extern "C" void kernel_launch(void* const* d_in, const int* in_sizes, int n_in,
                              void* d_out, int out_size, void* d_ws, size_t ws_size,
                              hipStream_t stream) {
    const int*   pos = (const int*)d_in[0];
    const int*   neg = (const int*)d_in[1];
    const float* emb = (const float*)d_in[2];
    const float* bh  = (const float*)d_in[3];
    const float* bt  = (const float*)d_in[4];
    const float* rwh = (const float*)d_in[5];
    const float* bwh = (const float*)d_in[6];
    const float* rwt = (const float*)d_in[7];
    const float* bwt = (const float*)d_in[8];
    float* ws  = (float*)d_ws;
    float* vg  = ws + OFF_V;
    float* wgp = ws + OFF_W;
    float* thg = ws + OFF_TH;
    float* rog = ws + OFF_RO;
    float* zkg = ws + OFF_ZK;
    float* out = (float*)d_out;

    k0_gelu <<<dim3(1024), dim3(256), 0, stream>>>(rwh, rwt, vg);
    k1_house<<<dim3(1024), dim3(256), 0, stream>>>(vg, wgp);
    k_ro    <<<dim3(512),  dim3(64),  0, stream>>>(bwt, rog, zkg);
    k2_th   <<<dim3(1024), dim3(64),  0, stream>>>(pos, emb, wgp, bwh, thg);
    k3_score<<<dim3(1024), dim3(256), 0, stream>>>(pos, neg, emb, bh, bt, wgp,
                                                   thg, rog, zkg, out);
}

// Round 6
// 87.811 us; speedup vs baseline: 2.0718x; 1.5276x over previous
//
#include <hip/hip_runtime.h>
#include <math.h>

#define DM1 63
#define WROW 64
#define RSIZE (DM1*WROW)   // 4032 floats per rel-side matrix
#define VSTR 68            // LDS row stride (272B: 16B-aligned per row)

typedef float f4 __attribute__((ext_vector_type(4)));

// d_ws float offsets
#define OFF_W   0u
#define SZ_W    (1024u*RSIZE)
#define OFF_TH  (OFF_W + SZ_W)
#define SZ_TH   (1024u*64u)
#define OFF_RO  (OFF_TH + SZ_TH)
#define SZ_RO   (512u*64u)
#define OFF_ZK  (OFF_RO + SZ_RO)

__device__ __forceinline__ float qreduce(float d) {
#if __has_builtin(__builtin_amdgcn_mov_dpp)
    int t = __builtin_amdgcn_mov_dpp(__float_as_int(d), 0xB1, 0xF, 0xF, true); // quad xor1
    d += __int_as_float(t);
    t = __builtin_amdgcn_mov_dpp(__float_as_int(d), 0x4E, 0xF, 0xF, true);     // quad xor2
    d += __int_as_float(t);
    return d;
#else
    d += __shfl_xor(d, 1);
    d += __shfl_xor(d, 2);
    return d;
#endif
}

// ---------------- K01: fused gelu + scale + Householder product, all in LDS.
// v' = gelu(w)*sqrt(2/n) lives in LDS; step: row -= (row.v')*v'.
// 4 lanes per row, 16 cols per lane; quad reduce via DPP.
#define K1LOAD(V, s) do { const f4* _vp = (const f4*)(vbase + (size_t)(s) * VSTR); \
    V##0 = _vp[0]; V##1 = _vp[1]; V##2 = _vp[2]; V##3 = _vp[3]; } while(0)

#define K1STEP(V) do { \
    f4 q01 = w0*V##0 + w1*V##1; \
    f4 q23 = w2*V##2 + w3*V##3; \
    f4 q = q01 + q23; \
    float d = (q[0] + q[1]) + (q[2] + q[3]); \
    d = qreduce(d); \
    w0 -= d*V##0; w1 -= d*V##1; w2 -= d*V##2; w3 -= d*V##3; } while(0)

__global__ __launch_bounds__(256) void k01_fused(const float* __restrict__ rwh,
                                                 const float* __restrict__ rwt,
                                                 float* __restrict__ wg) {
    int rs = blockIdx.x;               // 0..1023 : side*512 + r
    int side = rs >> 9, r = rs & 511;
    const float* rw = (side ? rwt : rwh) + (size_t)r * 3969;
    __shared__ __align__(16) float vv[DM1 * VSTR];
    __shared__ float sc[64];
    int tid = threadIdx.x;             // 256 threads

    // phase 1: gelu into LDS
    for (int idx = tid; idx < 3969; idx += 256) {
        int s = idx / 63, j = idx - s * 63;
        float x = rw[idx];
        vv[s * VSTR + j] = 0.5f * x * (1.f + erff(x * 0.70710678118654752f));
    }
    if (tid < DM1) vv[tid * VSTR + 63] = 0.f;   // zero pad col 63
    __syncthreads();

    // phase 2: per-step scale sqrt(2/sum(v^2)); 4 lanes per step-row
    if (tid < 252) {
        int s = tid >> 2, p = tid & 3;
        const float* vr = &vv[s * VSTR + p * 16];
        float sum = 0.f;
        #pragma unroll
        for (int j = 0; j < 16; j++) { float v = vr[j]; sum = fmaf(v, v, sum); }
        sum = qreduce(sum);
        if (p == 0) sc[s] = sqrtf(2.f / sum);
    }
    __syncthreads();

    // phase 3: pre-scale rows in place (col 63 stays 0)
    for (int idx = tid; idx < DM1 * 64; idx += 256) {
        int s = idx >> 6, j = idx & 63;
        vv[s * VSTR + j] *= sc[s];
    }
    __syncthreads();

    // phase 4: Householder product from LDS
    int lane = tid & 63, wv = tid >> 6;
    int row = wv * 16 + (lane >> 2);   // 0..63 (row 63 is a dummy)
    int p = lane & 3;                  // column quarter
    int c0 = p * 16;
    const float* vbase = &vv[c0];

    f4 w0, w1, w2, w3;
    #define IW(k, b) (((b) + (k)) == row ? 1.f : 0.f)
    w0 = (f4){IW(0,c0),    IW(1,c0),    IW(2,c0),    IW(3,c0)};
    w1 = (f4){IW(0,c0+4),  IW(1,c0+4),  IW(2,c0+4),  IW(3,c0+4)};
    w2 = (f4){IW(0,c0+8),  IW(1,c0+8),  IW(2,c0+8),  IW(3,c0+8)};
    w3 = (f4){IW(0,c0+12), IW(1,c0+12), IW(2,c0+12), IW(3,c0+12)};
    #undef IW

    f4 va0,va1,va2,va3, vb0,vb1,vb2,vb3, vc0,vc1,vc2,vc3, vd0,vd1,vd2,vd3;
    K1LOAD(va, 0); K1LOAD(vb, 1); K1LOAD(vc, 2); K1LOAD(vd, 3);
    #pragma unroll 1
    for (int s = 0; s < 56; s += 4) {
        K1STEP(va); K1LOAD(va, s + 4);
        K1STEP(vb); K1LOAD(vb, s + 5);
        K1STEP(vc); K1LOAD(vc, s + 6);
        K1STEP(vd); K1LOAD(vd, s + 7);
    }
    K1STEP(va); K1LOAD(va, 60);  // s=56
    K1STEP(vb); K1LOAD(vb, 61);  // s=57
    K1STEP(vc); K1LOAD(vc, 62);  // s=58
    K1STEP(vd);                  // s=59
    K1STEP(va);                  // s=60
    K1STEP(vb);                  // s=61
    K1STEP(vc);                  // s=62

    if (row < DM1) {
        f4* wo = (f4*)(wg + (size_t)rs * RSIZE + (size_t)row * WROW + c0);
        wo[0] = w0; wo[1] = w1; wo[2] = w2; wo[3] = w3;
    }
}

// ---------------- K_ro: tail boost constants per relation
__global__ void k_ro(const float* __restrict__ bwt, float* __restrict__ rog,
                     float* __restrict__ zkg) {
    int r = blockIdx.x, c = threadIdx.x;   // 64 threads
    float rov = (c < 63) ? tanhf(bwt[r * 63 + c]) * 0.015625f : 0.f;
    rog[r * 64 + c] = rov;
    float p = rov * rov;
    #pragma unroll
    for (int off = 32; off; off >>= 1) p += __shfl_xor(p, off);
    if (c == 0) {
        float v2 = p;
        float zeta = 1.f / (sqrtf(1.f - v2) + 1e-8f);
        zkg[r * 2]     = zeta;
        zkg[r * 2 + 1] = (zeta - 1.f) / (v2 + 1e-9f);
    }
}

// ---------------- K2: head transform th[b][0..63] (rotation + boost), lane = out dim
__global__ void k2_th(const int* __restrict__ pos, const float* __restrict__ emb,
                      const float* __restrict__ wg, const float* __restrict__ bwh,
                      float* __restrict__ thg) {
    int b = blockIdx.x, c = threadIdx.x;   // 64 threads
    int u = pos[b * 3], r = pos[b * 3 + 1];
    const float* hrow = emb + (size_t)u * 64;          // wave-uniform -> scalar
    const float* wr = wg + (size_t)r * RSIZE;          // head side (rs = r)
    float xnc = 0.f;
    for (int d = 0; d < DM1; d++) xnc = fmaf(hrow[1 + d], wr[d * WROW + c], xnc);
    float rov = (c < 63) ? tanhf(bwh[r * 63 + c]) * 0.015625f : 0.f;
    float p = rov * rov, q = xnc * rov;
    #pragma unroll
    for (int off = 32; off; off >>= 1) { p += __shfl_xor(p, off); q += __shfl_xor(q, off); }
    float v2 = p, dot = q;
    float zeta = 1.f / (sqrtf(1.f - v2) + 1e-8f);
    float k = (zeta - 1.f) / (v2 + 1e-9f);
    float x0 = hrow[0];
    float val;
    int idx;
    if (c < 63) { val = fmaf(-zeta * x0, rov, xnc) + k * rov * dot; idx = c + 1; }
    else        { val = zeta * x0 - zeta * dot;                      idx = 0;    }
    thg[b * 64 + idx] = val;
}

// ---------------- K3: scoring. block = batch row, thread = tail candidate
__global__ __launch_bounds__(256) void k3_score(
    const int* __restrict__ pos, const int* __restrict__ neg,
    const float* __restrict__ emb, const float* __restrict__ bh,
    const float* __restrict__ bt, const float* __restrict__ wg,
    const float* __restrict__ thg, const float* __restrict__ rog,
    const float* __restrict__ zkg, float* __restrict__ out) {
    int b = blockIdx.x, j = threadIdx.x;
    int u = pos[b * 3], r = pos[b * 3 + 1];
    int v = (j == 0) ? pos[b * 3 + 2] : neg[b * 255 + j - 1];
    const float4* tp4 = (const float4*)(emb + (size_t)v * 64);
    const float* wt = wg + (size_t)(512 + r) * RSIZE;   // tail side
    const float* ro = rog + r * 64;                     // wave-uniform
    const float* th = thg + b * 64;                     // wave-uniform
    float zeta = zkg[2 * r], kk = zkg[2 * r + 1];

    float xn[64];
    #pragma unroll
    for (int c = 0; c < 64; c++) xn[c] = 0.f;
    float x0;
    {   // peel q=0: elements t[0..3] -> x0 and d=0,1,2
        float4 tv = tp4[0];
        x0 = tv.x;
        #pragma unroll
        for (int c = 0; c < 64; c++) xn[c] = fmaf(tv.y, wt[c], xn[c]);
        #pragma unroll
        for (int c = 0; c < 64; c++) xn[c] = fmaf(tv.z, wt[64 + c], xn[c]);
        #pragma unroll
        for (int c = 0; c < 64; c++) xn[c] = fmaf(tv.w, wt[128 + c], xn[c]);
    }
    #pragma unroll 1
    for (int q = 1; q < 16; q++) {      // d = 4q-1 .. 4q+2
        float4 tv = tp4[q];
        const float* wq = wt + (4 * q - 1) * 64;
        #pragma unroll
        for (int c = 0; c < 64; c++) xn[c] = fmaf(tv.x, wq[c], xn[c]);
        #pragma unroll
        for (int c = 0; c < 64; c++) xn[c] = fmaf(tv.y, wq[64 + c], xn[c]);
        #pragma unroll
        for (int c = 0; c < 64; c++) xn[c] = fmaf(tv.z, wq[128 + c], xn[c]);
        #pragma unroll
        for (int c = 0; c < 64; c++) xn[c] = fmaf(tv.w, wq[192 + c], xn[c]);
    }
    // boost(tail) + score. ro[63]=0, xn[63]=0 (W col 63 zeroed).
    float dot = 0.f;
    #pragma unroll
    for (int c = 0; c < 64; c++) dot = fmaf(xn[c], ro[c], dot);
    float tt0 = zeta * x0 - zeta * dot;
    float d0 = tt0 - th[0];
    float acc = -d0 * d0;
    float A = fmaf(kk, dot, -zeta * x0);   // tt[1+c] = xn[c] + A*ro[c]
    #pragma unroll
    for (int c = 0; c < 63; c++) {
        float ttc = fmaf(A, ro[c], xn[c]);
        float dd = ttc - th[1 + c];
        acc = fmaf(dd, dd, acc);
    }
    out[b * 256 + j] = 0.85f - acc + tanhf(bh[u]) + tanhf(bt[v]);
}

extern "C" void kernel_launch(void* const* d_in, const int* in_sizes, int n_in,
                              void* d_out, int out_size, void* d_ws, size_t ws_size,
                              hipStream_t stream) {
    const int*   pos = (const int*)d_in[0];
    const int*   neg = (const int*)d_in[1];
    const float* emb = (const float*)d_in[2];
    const float* bh  = (const float*)d_in[3];
    const float* bt  = (const float*)d_in[4];
    const float* rwh = (const float*)d_in[5];
    const float* bwh = (const float*)d_in[6];
    const float* rwt = (const float*)d_in[7];
    const float* bwt = (const float*)d_in[8];
    float* ws  = (float*)d_ws;
    float* wgp = ws + OFF_W;
    float* thg = ws + OFF_TH;
    float* rog = ws + OFF_RO;
    float* zkg = ws + OFF_ZK;
    float* out = (float*)d_out;

    k01_fused<<<dim3(1024), dim3(256), 0, stream>>>(rwh, rwt, wgp);
    k_ro     <<<dim3(512),  dim3(64),  0, stream>>>(bwt, rog, zkg);
    k2_th    <<<dim3(1024), dim3(64),  0, stream>>>(pos, emb, wgp, bwh, thg);
    k3_score <<<dim3(1024), dim3(256), 0, stream>>>(pos, neg, emb, bh, bt, wgp,
                                                    thg, rog, zkg, out);
}